// Round 18
// baseline (61.192 us; speedup 1.0000x reference)
//
#include <hip/hip_runtime.h>
#include <hip/hip_bf16.h>
#include <hip/hip_fp16.h>

// ---------------- problem constants ----------------
namespace {
constexpr int kB = 1, kT = 2, kV = 3;
constexpr int kGH = 32, kGW = 64;
constexpr int kNG = kV * kGH * kGW;      // 6144 gaussians per (b,t)
constexpr int kNBT = kB * kT;            // 2
constexpr int kNI = kNBT * kV;           // 6 render instances
constexpr int kH = 224, kW = 448;
constexpr int kHW = kH * kW;             // 100352

// tile rasterizer: 64x4 pixels per 256-thread WG, 5x5 footprint.
constexpr int kTX = 64, kTY = 4;
constexpr int kTilesX = kW / kTX;        // 7
constexpr int kTilesY = kH / kTY;        // 56
constexpr int kNTiles = kTilesX * kTilesY; // 392
constexpr int kNBins = kNI * kNTiles;    // 2352
constexpr int kCAP = 512;                // per-tile capacity (never hit: r9/r10 verified)
constexpr int kMaxEnt = kNI * kNG;       // 36864 (< 65536 -> u16 ids)

// output bases (floats)
constexpr size_t RGB_SZ = (size_t)kNI * 3 * kHW;
constexpr size_t A_SZ   = (size_t)kNI * kHW;
constexpr size_t O_RGB_STA = 0;
constexpr size_t O_RGB_DYN = O_RGB_STA + RGB_SZ;
constexpr size_t O_RGB_ALL = O_RGB_DYN + RGB_SZ;
constexpr size_t O_A_STA   = O_RGB_ALL + RGB_SZ;
constexpr size_t O_A_DYN   = O_A_STA + A_SZ;
constexpr size_t O_A_ALL   = O_A_DYN + A_SZ;
constexpr size_t O_SEM     = O_A_ALL + A_SZ;
constexpr size_t O_SM      = O_SEM + A_SZ;
constexpr size_t O_TR      = O_SM + 1;

// workspace layout (bytes), total ~4.2 MB
constexpr size_t WS_W2C   = 128;   // f32[6*16] inverses (written by k_zero WG0)
constexpr size_t WS_CNTR  = 512;   // entCnt @+0, sigmaSum[6] @+16, cnt[6] @+48
constexpr size_t WS_TCNT  = 1024;                                    // int[kNBins]
constexpr size_t WS_TTOUCH= WS_TCNT + (size_t)kNBins * 4;            // int[kNBins] (no zeroing needed)
constexpr size_t WS_TLIST = WS_TTOUCH + (size_t)kNBins * 4;          // u16[kNBins*kCAP]
constexpr size_t WS_PAY   = WS_TLIST + (size_t)kNBins * kCAP * 2;    // f32[12*kMaxEnt]

// zero range: [WS_CNTR, WS_TCNT + kNBins*4) = 2480 ints
constexpr int kZeroInts = (int)((WS_TCNT + (size_t)kNBins * 4 - WS_CNTR) / 4);

// k_tile shared memory overlay (bytes)
constexpr int SH_KEY  = 0;                  // u64[kCAP]          = 4096
constexpr int SH_A    = 4096;               // float4[kCAP+8]     = 8320
constexpr int SH_B    = 12416;              // float2[kCAP+8]     = 4160 -> 16576
constexpr int SH_STG  = 0;                  // float[12][272] overlay = 13056 (< 16576)
constexpr int kStgP   = 272;                // plane stride (floats); row stride 68 (bank-pad)
constexpr int SH_SIZE = 16576;

__device__ __forceinline__ float clip01(float x) { return fminf(fmaxf(x, 0.f), 1.f); }
__device__ __forceinline__ unsigned long long packkey(int zbits, int ikey) {
    return ((unsigned long long)(unsigned)zbits << 32) | (unsigned)ikey;
}
__device__ __forceinline__ float packh2(float a, float b) {
    __half2 h = __floats2half2_rn(a, b);
    return __uint_as_float(*reinterpret_cast<unsigned*>(&h));
}
__device__ __forceinline__ float2 unpackh2(float f) {
    unsigned u = __float_as_uint(f);
    return __half22float2(*reinterpret_cast<__half2*>(&u));
}
}

// ---------------- kernels ----------------

// zero counters + tileCnt; WG0 lanes 0..5 also invert the 6 c2w matrices into ws
__global__ __launch_bounds__(256) void k_zero(int* __restrict__ zp,
                                              const float* __restrict__ c2w,
                                              float* __restrict__ w2c) {
    int i = blockIdx.x * 256 + threadIdx.x;
    if (i < kZeroInts) zp[i] = 0;
    if (blockIdx.x == 0 && threadIdx.x < kNI) {
        int inst = threadIdx.x;
        float m[4][8];
        const float* A = c2w + (size_t)inst * 16;
        for (int r = 0; r < 4; ++r)
            for (int cc = 0; cc < 4; ++cc) { m[r][cc] = A[r * 4 + cc]; m[r][cc + 4] = (r == cc) ? 1.f : 0.f; }
        for (int col = 0; col < 4; ++col) {
            int piv = col; float mx = fabsf(m[col][col]);
            for (int r = col + 1; r < 4; ++r) { float a = fabsf(m[r][col]); if (a > mx) { mx = a; piv = r; } }
            if (piv != col)
                for (int cc = 0; cc < 8; ++cc) { float tt = m[col][cc]; m[col][cc] = m[piv][cc]; m[piv][cc] = tt; }
            float inv = 1.f / m[col][col];
            for (int cc = 0; cc < 8; ++cc) m[col][cc] *= inv;
            for (int r = 0; r < 4; ++r) {
                if (r == col) continue;
                float f = m[r][col];
                for (int cc = 0; cc < 8; ++cc) m[r][cc] -= f * m[col][cc];
            }
        }
        for (int r = 0; r < 4; ++r)
            for (int cc = 0; cc < 4; ++cc) w2c[(size_t)inst * 16 + r * 4 + cc] = m[r][cc + 4];
    }
}

// project + bin. One thread per (bt,g); inner loop over the 3 rendered views shares
// all per-gaussian loads + world transform (views differ only in w2c + intrinsics).
__global__ void k_pre(const float* __restrict__ centers, const float* __restrict__ scale,
                      const float* __restrict__ feat, const float* __restrict__ opac,
                      const float* __restrict__ bgp, const float* __restrict__ intr,
                      const float* __restrict__ fpose, const float* __restrict__ w2c,
                      int* __restrict__ entCnt, float* __restrict__ sigmaSum, int* __restrict__ cnt,
                      int* __restrict__ tileCnt, unsigned short* __restrict__ tileList,
                      float* __restrict__ pay) {
    int bt = blockIdx.y;                      // 0..1
    int g = blockIdx.x * 256 + threadIdx.x;   // grid exact: 6144 = 24*256
    int b = bt / kT;                          // 0
    int lane = threadIdx.x & 63;

    // ---- per-(bt,g) loads, shared across the 3 views ----
    const float* c = centers + ((size_t)bt * kNG + g) * 3;
    float c0 = c[0], c1 = c[1], c2 = c[2];
    const float* sp = scale + ((size_t)bt * kNG + g) * 3;
    float sf = (sp[0] + sp[1] + sp[2]) / 3.f;
    float asf = fabsf(sf);
    float op = clip01(opac[(size_t)bt * kNG + g]);
    float bg = bgp[(size_t)bt * kNG + g];
    const float* fc = feat + ((size_t)bt * kNG + g) * 3;
    float r = clip01(fc[0]), gc = clip01(fc[1]), bcl = clip01(fc[2]);

    const float* P = fpose + (size_t)b * 16;
    float wx[4];
#pragma unroll
    for (int i = 0; i < 4; ++i)
        wx[i] = P[i * 4 + 0] * c0 + P[i * 4 + 1] * c1 + P[i * 4 + 2] * c2 + P[i * 4 + 3];

    float dyn = clip01(1.f - bg);
    float aAll = op;
    float aDyn = clip01(op * dyn);
    float aSta = clip01(op * (1.f - dyn));
    if (aDyn <= 1e-5f) aDyn = 0.f;
    if (aSta <= 1e-5f) aSta = 0.f;

    for (int v = 0; v < kV; ++v) {
        int inst = bt * kV + v;
        const float* M = w2c + (size_t)inst * 16;   // uniform address -> scalar loads
        float camx = M[0] * wx[0] + M[1] * wx[1] + M[2] * wx[2] + M[3] * wx[3];
        float camy = M[4] * wx[0] + M[5] * wx[1] + M[6] * wx[2] + M[7] * wx[3];
        float camz = M[8] * wx[0] + M[9] * wx[1] + M[10] * wx[2] + M[11] * wx[3];

        bool zok = (camz > 0.001f) && isfinite(camx) && isfinite(camy) && isfinite(camz);
        bool valid0 = zok && (op > 1e-5f);

        const float* it = intr + ((size_t)b * kV + v) * 4;
        float fx = it[0], fy = it[1], cx = it[2], cy = it[3];
        float u = camx * fx / camz + cx;
        float vv = camy * fy / camz + cy;
        float sg = fminf(fmaxf((fx + fy) * 0.5f * asf / fmaxf(camz, 0.001f), 0.75f), 10.f);

        bool inb = (u >= -3.f) && (u <= (float)kW + 2.f) && (vv >= -3.f) && (vv <= (float)kH + 2.f);
        bool statsValid = valid0 && inb;

        // wave-reduced sigma/cnt stats (1 atomic pair per wave per view)
        float ssum = statsValid ? sg : 0.f;
        int scnt = statsValid ? 1 : 0;
#pragma unroll
        for (int o = 32; o > 0; o >>= 1) {
            ssum += __shfl_down(ssum, o);
            scnt += __shfl_down(scnt, o);
        }
        if (lane == 0 && scnt > 0) {
            atomicAdd(&sigmaSum[inst], ssum);
            atomicAdd(&cnt[inst], scnt);
        }

        int x0 = (int)floorf(u);
        int y0 = (int)floorf(vv);
        bool emit = statsValid && (x0 >= -2) && (x0 <= kW + 1) && (y0 >= -2) && (y0 <= kH + 1);

        // wave-aggregated entry allocation (1 atomic per wave per view)
        unsigned long long m = __ballot(emit);
        int base = 0;
        if (m) {
            int leader = __ffsll((long long)m) - 1;
            if (lane == leader) base = atomicAdd(entCnt, __popcll(m));
            base = __shfl(base, leader);
        }
        if (emit) {
            int e = base + __popcll(m & ((1ULL << lane) - 1ULL));

            float4* p4 = (float4*)(pay + (size_t)e * 12);
            int keybits = (g << 16) | e;
            p4[0] = make_float4(u, vv, 1.f / fmaxf(sg, 0.001f), aSta);
            p4[1] = make_float4(aDyn, aAll, r, gc);
            p4[2] = make_float4(bcl, camz, __int_as_float(keybits), 0.f);

            // overlapping 64x4 tiles of the footprint [x0-2,x0+2]x[y0-2,y0+2]
            int ilo = x0 - 2 < 0 ? 0 : (x0 - 2) / kTX;
            int ihi = min(kTilesX - 1, (x0 + 2) / kTX);
            int jlo = y0 - 2 < 0 ? 0 : (y0 - 2) / kTY;
            int jhi = min(kTilesY - 1, (y0 + 2) / kTY);
            for (int j = jlo; j <= jhi; ++j)
                for (int i = ilo; i <= ihi; ++i) {
                    int bin = inst * kNTiles + j * kTilesX + i;
                    int idx = atomicAdd(&tileCnt[bin], 1);
                    if (idx < kCAP) tileList[(size_t)bin * kCAP + idx] = (unsigned short)e;
                }
        }
    }
}

// tiled rasterizer: gather own bin, rank-sort by (z,g); composite with 16x4 wave
// sub-blocks (__any(keep) skip); LDS re-map; cooperative float4 writeout (1KB/wave-instr).
__global__ __launch_bounds__(256) void k_tile(const int* __restrict__ tileCnt,
                                              const unsigned short* __restrict__ tileList,
                                              const float* __restrict__ pay,
                                              const float* __restrict__ sem,
                                              float* __restrict__ out,
                                              int* __restrict__ tileTouch) {
    __shared__ __align__(16) char smem[SH_SIZE];
    __shared__ int shT[4];
    unsigned long long* shKey = (unsigned long long*)(smem + SH_KEY);
    float4* shA = (float4*)(smem + SH_A);
    float2* shB = (float2*)(smem + SH_B);
    float*  stage = (float*)(smem + SH_STG);   // overlays shKey/shA/shB-head after composite

    int t = threadIdx.x;
    int tile = blockIdx.x;
    int inst = blockIdx.y;
    int bin = inst * kNTiles + tile;
    int N = tileCnt[bin];
    if (N > kCAP) N = kCAP;

    // gather 2 slots per thread (kCAP = 2*256); records in registers until rank known
    unsigned long long kA = ~0ULL, kB = ~0ULL;
    float4 aA, aB; float2 bA, bB;
#define GATHER(i, kq, aq, bq)                                              \
    {   if (i < N) {                                                       \
            int e = tileList[(size_t)bin * kCAP + i];                      \
            const float4* pp = (const float4*)(pay + (size_t)e * 12);      \
            float4 p0 = pp[0], p1 = pp[1], p2 = pp[2];                     \
            kq = packkey(__float_as_int(p2.y), __float_as_int(p2.z));      \
            shKey[i] = kq;                                                 \
            aq = make_float4(p0.x, p0.y, p0.z, packh2(p0.w, p1.x));        \
            bq = make_float2(packh2(p1.y, p1.z), packh2(p1.w, p2.x));      \
        } }
    GATHER(t, kA, aA, bA)
    GATHER(t + 256, kB, aB, bB)
#undef GATHER
    __syncthreads();

    // rank sort (keys unique: low bits hold entry id)
    int rA = 0, rB = 0;
    for (int j = 0; j < N; ++j) {
        unsigned long long kj = shKey[j];
        rA += (kj < kA); rB += (kj < kB);
    }
    __syncthreads();
    if (t < N)       { shA[rA] = aA; shB[rA] = bA; }
    if (t + 256 < N) { shA[rB] = aB; shB[rB] = bB; }
    if (t < 8) {   // zero padding slots for the prefetch pipeline (no-op records)
        shA[N + t] = make_float4(0.f, 0.f, 0.f, 0.f);
        shB[N + t] = make_float2(0.f, 0.f);
    }
    __syncthreads();

    // composite: wave w owns 16x4 sub-block; lane -> (x = w*16 + (lane&15), y = lane>>4)
    int tx = (tile % kTilesX) * kTX;
    int ty = (tile / kTilesX) * kTY;
    int wv = t >> 6, lane = t & 63;
    int clx = wv * 16 + (lane & 15);     // local x in tile
    int cly = lane >> 4;                 // local y in tile
    float fpx = (float)(tx + clx), fpy = (float)(ty + cly);

    float ad0 = 0.f, ad1 = 0.f, ad2 = 0.f;
    float sr0 = 0.f, sg0 = 0.f, sb0 = 0.f;
    float sr1 = 0.f, sg1 = 0.f, sb1 = 0.f;
    float sr2 = 0.f, sg2 = 0.f, sb2 = 0.f;

    float4 Ac = shA[0]; float2 Bc = shB[0];
    for (int k = 0; k < N; ++k) {
        float4 An = shA[k + 1]; float2 Bn = shB[k + 1];   // unconditional prefetch (pad-safe)
        float dxc = fpx - floorf(Ac.x);
        float dyc = fpy - floorf(Ac.y);
        bool keep = (dxc >= -2.f) && (dxc <= 2.f) && (dyc >= -2.f) && (dyc <= 2.f);
        if (__any(keep)) {                                // skipped iters are exact no-ops
            float du = (Ac.x - fpx) * Ac.z;
            float dv = (Ac.y - fpy) * Ac.z;
            float lb = __expf(-0.5f * (du * du + dv * dv));
            lb = keep ? lb : 0.f;
            float2 sd = unpackh2(Ac.w);   // aSta, aDyn
            float2 ar = unpackh2(Bc.x);   // aAll, r
            float2 gb = unpackh2(Bc.y);   // g, b
            // ad* stays in [0, 0.999] by induction -> clip01(1-ad*) == 1-ad* (exact)
            float la, Tt, ct;
            la = fminf(lb * sd.x, 0.999f);
            Tt = 1.f - ad0; ct = la * Tt;
            ad0 = fminf(ad0 + ct, 0.999f);
            sr0 += ar.y * ct; sg0 += gb.x * ct; sb0 += gb.y * ct;
            la = fminf(lb * sd.y, 0.999f);
            Tt = 1.f - ad1; ct = la * Tt;
            ad1 = fminf(ad1 + ct, 0.999f);
            sr1 += ar.y * ct; sg1 += gb.x * ct; sb1 += gb.y * ct;
            la = fminf(lb * ar.x, 0.999f);
            Tt = 1.f - ad2; ct = la * Tt;
            ad2 = fminf(ad2 + ct, 0.999f);
            sr2 += ar.y * ct; sg2 += gb.x * ct; sb2 += gb.y * ct;
        }
        Ac = An; Bc = Bn;
    }

    // touch: per-wave ballot (bijective pixel mapping -> grouping irrelevant)
    unsigned long long tm = __ballot(ad2 > 1e-6f);
    if ((t & 63) == 0) shT[t >> 6] = __popcll(tm);

    // stage 12 outputs in LDS (overlays sort buffers; stride 68 avoids bank conflicts)
    __syncthreads();   // all composite reads of shA/shB done
    int ci = cly * 68 + clx;
    stage[0 * kStgP + ci] = clip01(sr0);
    stage[1 * kStgP + ci] = clip01(sg0);
    stage[2 * kStgP + ci] = clip01(sb0);
    stage[3 * kStgP + ci] = clip01(sr1);
    stage[4 * kStgP + ci] = clip01(sg1);
    stage[5 * kStgP + ci] = clip01(sb1);
    stage[6 * kStgP + ci] = clip01(sr2);
    stage[7 * kStgP + ci] = clip01(sg2);
    stage[8 * kStgP + ci] = clip01(sb2);
    stage[9 * kStgP + ci] = ad0;
    stage[10 * kStgP + ci] = ad1;
    stage[11 * kStgP + ci] = ad2;
    __syncthreads();

    if (t == 0) tileTouch[bin] = shT[0] + shT[1] + shT[2] + shT[3];

    // cooperative float4 writeout: 13 planes x 4 rows x 16 float4-lanes = 832 slots.
    // Wave-instruction segment = 64 lanes x 16B = 1KB (fill-kernel-proven 6.3TB/s shape).
    for (int s = t; s < 13 * 64; s += 256) {
        int p = s >> 6;                 // plane 0..12
        int rl = s & 63;
        int row = rl >> 4, c4 = rl & 15;
        size_t rowoff = (size_t)(ty + row) * kW + tx + c4 * 4;
        float4 v4;
        if (p == 12) v4 = *(const float4*)(sem + (size_t)inst * kHW + rowoff);
        else         v4 = *(const float4*)(stage + p * kStgP + row * 68 + c4 * 4);
        size_t pb;
        if (p < 9)       pb = (size_t)(p / 3) * RGB_SZ + ((size_t)inst * 3 + (p % 3)) * kHW;
        else if (p < 12) pb = O_A_STA + (size_t)(p - 9) * A_SZ + (size_t)inst * kHW;
        else             pb = O_SEM + (size_t)inst * kHW;
        *(float4*)(out + pb + rowoff) = v4;
    }
}

// 384-thread finalize: wave w reduces instance w's touch counts; LDS combine
__global__ __launch_bounds__(384) void k_fin(const float* __restrict__ sigmaSum,
                                             const int* __restrict__ cnt,
                                             const int* __restrict__ tileTouch,
                                             float* __restrict__ out) {
    __shared__ float shSm[kNI], shTr[kNI];
    int w = threadIdx.x >> 6;      // instance 0..5
    int lane = threadIdx.x & 63;
    int s = 0;
    for (int i = lane; i < kNTiles; i += 64) s += tileTouch[w * kNTiles + i];
#pragma unroll
    for (int o = 32; o > 0; o >>= 1) s += __shfl_down(s, o);
    if (lane == 0) {
        shSm[w] = sigmaSum[w] / fmaxf((float)cnt[w], 1.f);
        shTr[w] = (float)s / (float)kHW;
    }
    __syncthreads();
    if (threadIdx.x == 0) {
        float sm = 0.f, tr = 0.f;
        for (int i = 0; i < kNI; ++i) { sm += shSm[i]; tr += shTr[i]; }
        out[O_SM] = sm / (float)kNI;
        out[O_TR] = tr / (float)kNI;
    }
}

// ---------------- launch ----------------
extern "C" void kernel_launch(void* const* d_in, const int* in_sizes, int n_in,
                              void* d_out, int out_size, void* d_ws, size_t ws_size,
                              hipStream_t stream) {
    const float* centers = (const float*)d_in[0];
    const float* scal    = (const float*)d_in[1];
    const float* feat    = (const float*)d_in[2];
    const float* opac    = (const float*)d_in[3];
    const float* bgp     = (const float*)d_in[4];
    const float* sem     = (const float*)d_in[5];
    const float* intr    = (const float*)d_in[6];
    const float* c2w     = (const float*)d_in[7];
    const float* fpose   = (const float*)d_in[8];
    float* out = (float*)d_out;
    char* ws = (char*)d_ws;

    float* w2c      = (float*)(ws + WS_W2C);
    int*   entCnt   = (int*)(ws + WS_CNTR);
    float* sigmaSum = (float*)(ws + WS_CNTR + 16);
    int*   cnt      = (int*)(ws + WS_CNTR + 48);
    int*   tileCnt  = (int*)(ws + WS_TCNT);
    int*   tileTouch= (int*)(ws + WS_TTOUCH);
    unsigned short* tileList = (unsigned short*)(ws + WS_TLIST);
    float* pay      = (float*)(ws + WS_PAY);

    k_zero<<<(kZeroInts + 255) / 256, 256, 0, stream>>>((int*)(ws + WS_CNTR), c2w, w2c);

    dim3 gpre(kNG / 256, kNBT);
    k_pre<<<gpre, 256, 0, stream>>>(centers, scal, feat, opac, bgp, intr, fpose, w2c,
                                    entCnt, sigmaSum, cnt, tileCnt, tileList, pay);

    dim3 gtile(kNTiles, kNI);
    k_tile<<<gtile, 256, 0, stream>>>(tileCnt, tileList, pay, sem, out, tileTouch);

    k_fin<<<1, 384, 0, stream>>>(sigmaSum, cnt, tileTouch, out);
}

// Round 19
// 60.171 us; speedup vs baseline: 1.0170x; 1.0170x over previous
//
#include <hip/hip_runtime.h>
#include <hip/hip_bf16.h>
#include <hip/hip_fp16.h>

// ---------------- problem constants ----------------
namespace {
constexpr int kB = 1, kT = 2, kV = 3;
constexpr int kGH = 32, kGW = 64;
constexpr int kNG = kV * kGH * kGW;      // 6144 gaussians per (b,t)
constexpr int kNBT = kB * kT;            // 2
constexpr int kNI = kNBT * kV;           // 6 render instances
constexpr int kH = 224, kW = 448;
constexpr int kHW = kH * kW;             // 100352

// tile rasterizer: 64x4 pixels per 256-thread WG, 5x5 footprint.
constexpr int kTX = 64, kTY = 4;
constexpr int kTilesX = kW / kTX;        // 7
constexpr int kTilesY = kH / kTY;        // 56
constexpr int kNTiles = kTilesX * kTilesY; // 392
constexpr int kNBins = kNI * kNTiles;    // 2352
constexpr int kCAP = 512;                // per-tile capacity (never hit: r9/r10 verified)
constexpr int kMaxEnt = kNI * kNG;       // 36864 (< 65536 -> u16 ids)

// output bases (floats)
constexpr size_t RGB_SZ = (size_t)kNI * 3 * kHW;
constexpr size_t A_SZ   = (size_t)kNI * kHW;
constexpr size_t O_RGB_STA = 0;
constexpr size_t O_RGB_DYN = O_RGB_STA + RGB_SZ;
constexpr size_t O_RGB_ALL = O_RGB_DYN + RGB_SZ;
constexpr size_t O_A_STA   = O_RGB_ALL + RGB_SZ;
constexpr size_t O_A_DYN   = O_A_STA + A_SZ;
constexpr size_t O_A_ALL   = O_A_DYN + A_SZ;
constexpr size_t O_SEM     = O_A_ALL + A_SZ;
constexpr size_t O_SM      = O_SEM + A_SZ;
constexpr size_t O_TR      = O_SM + 1;

// workspace layout (bytes), total ~4.2 MB
constexpr size_t WS_W2C   = 128;   // f32[6*16] inverses (written by k_zero WG0)
constexpr size_t WS_CNTR  = 512;   // entCnt @+0, sigmaSum[6] @+16, cnt[6] @+48
constexpr size_t WS_TCNT  = 1024;                                    // int[kNBins]
constexpr size_t WS_TTOUCH= WS_TCNT + (size_t)kNBins * 4;            // int[kNBins] (no zeroing needed)
constexpr size_t WS_TLIST = WS_TTOUCH + (size_t)kNBins * 4;          // u16[kNBins*kCAP]
constexpr size_t WS_PAY   = WS_TLIST + (size_t)kNBins * kCAP * 2;    // f32[12*kMaxEnt]

// zero range: [WS_CNTR, WS_TCNT + kNBins*4) = 2480 ints
constexpr int kZeroInts = (int)((WS_TCNT + (size_t)kNBins * 4 - WS_CNTR) / 4);

// k_tile shared memory overlay (bytes)
constexpr int SH_KEY  = 0;                  // u64[kCAP]          = 4096
constexpr int SH_A    = 4096;               // float4[kCAP+8]     = 8320
constexpr int SH_B    = 12416;              // float2[kCAP+8]     = 4160 -> 16576
constexpr int SH_STG  = 0;                  // float[12][272] overlay = 13056 (< 16576)
constexpr int kStgP   = 272;                // plane stride (floats); row stride 68 (bank-pad)
constexpr int SH_SIZE = 16576;

__device__ __forceinline__ float clip01(float x) { return fminf(fmaxf(x, 0.f), 1.f); }
__device__ __forceinline__ unsigned long long packkey(int zbits, int ikey) {
    return ((unsigned long long)(unsigned)zbits << 32) | (unsigned)ikey;
}
__device__ __forceinline__ float packh2(float a, float b) {
    __half2 h = __floats2half2_rn(a, b);
    return __uint_as_float(*reinterpret_cast<unsigned*>(&h));
}
__device__ __forceinline__ float2 unpackh2(float f) {
    unsigned u = __float_as_uint(f);
    return __half22float2(*reinterpret_cast<__half2*>(&u));
}
}

// ---------------- kernels ----------------

// zero counters + tileCnt; WG0 lanes 0..5 also invert the 6 c2w matrices into ws
__global__ __launch_bounds__(256) void k_zero(int* __restrict__ zp,
                                              const float* __restrict__ c2w,
                                              float* __restrict__ w2c) {
    int i = blockIdx.x * 256 + threadIdx.x;
    if (i < kZeroInts) zp[i] = 0;
    if (blockIdx.x == 0 && threadIdx.x < kNI) {
        int inst = threadIdx.x;
        float m[4][8];
        const float* A = c2w + (size_t)inst * 16;
        for (int r = 0; r < 4; ++r)
            for (int cc = 0; cc < 4; ++cc) { m[r][cc] = A[r * 4 + cc]; m[r][cc + 4] = (r == cc) ? 1.f : 0.f; }
        for (int col = 0; col < 4; ++col) {
            int piv = col; float mx = fabsf(m[col][col]);
            for (int r = col + 1; r < 4; ++r) { float a = fabsf(m[r][col]); if (a > mx) { mx = a; piv = r; } }
            if (piv != col)
                for (int cc = 0; cc < 8; ++cc) { float tt = m[col][cc]; m[col][cc] = m[piv][cc]; m[piv][cc] = tt; }
            float inv = 1.f / m[col][col];
            for (int cc = 0; cc < 8; ++cc) m[col][cc] *= inv;
            for (int r = 0; r < 4; ++r) {
                if (r == col) continue;
                float f = m[r][col];
                for (int cc = 0; cc < 8; ++cc) m[r][cc] -= f * m[col][cc];
            }
        }
        for (int r = 0; r < 4; ++r)
            for (int cc = 0; cc < 4; ++cc) w2c[(size_t)inst * 16 + r * 4 + cc] = m[r][cc + 4];
    }
}

// project + bin. One thread per (bt,g); inner loop over the 3 rendered views shares
// all per-gaussian loads + world transform (views differ only in w2c + intrinsics).
__global__ void k_pre(const float* __restrict__ centers, const float* __restrict__ scale,
                      const float* __restrict__ feat, const float* __restrict__ opac,
                      const float* __restrict__ bgp, const float* __restrict__ intr,
                      const float* __restrict__ fpose, const float* __restrict__ w2c,
                      int* __restrict__ entCnt, float* __restrict__ sigmaSum, int* __restrict__ cnt,
                      int* __restrict__ tileCnt, unsigned short* __restrict__ tileList,
                      float* __restrict__ pay) {
    int bt = blockIdx.y;                      // 0..1
    int g = blockIdx.x * 256 + threadIdx.x;   // grid exact: 6144 = 24*256
    int b = bt / kT;                          // 0
    int lane = threadIdx.x & 63;

    // ---- per-(bt,g) loads, shared across the 3 views ----
    const float* c = centers + ((size_t)bt * kNG + g) * 3;
    float c0 = c[0], c1 = c[1], c2 = c[2];
    const float* sp = scale + ((size_t)bt * kNG + g) * 3;
    float sf = (sp[0] + sp[1] + sp[2]) / 3.f;
    float asf = fabsf(sf);
    float op = clip01(opac[(size_t)bt * kNG + g]);
    float bg = bgp[(size_t)bt * kNG + g];
    const float* fc = feat + ((size_t)bt * kNG + g) * 3;
    float r = clip01(fc[0]), gc = clip01(fc[1]), bcl = clip01(fc[2]);

    const float* P = fpose + (size_t)b * 16;
    float wx[4];
#pragma unroll
    for (int i = 0; i < 4; ++i)
        wx[i] = P[i * 4 + 0] * c0 + P[i * 4 + 1] * c1 + P[i * 4 + 2] * c2 + P[i * 4 + 3];

    float dyn = clip01(1.f - bg);
    float aAll = op;
    float aDyn = clip01(op * dyn);
    float aSta = clip01(op * (1.f - dyn));
    if (aDyn <= 1e-5f) aDyn = 0.f;
    if (aSta <= 1e-5f) aSta = 0.f;

    for (int v = 0; v < kV; ++v) {
        int inst = bt * kV + v;
        const float* M = w2c + (size_t)inst * 16;   // uniform address -> scalar loads
        float camx = M[0] * wx[0] + M[1] * wx[1] + M[2] * wx[2] + M[3] * wx[3];
        float camy = M[4] * wx[0] + M[5] * wx[1] + M[6] * wx[2] + M[7] * wx[3];
        float camz = M[8] * wx[0] + M[9] * wx[1] + M[10] * wx[2] + M[11] * wx[3];

        bool zok = (camz > 0.001f) && isfinite(camx) && isfinite(camy) && isfinite(camz);
        bool valid0 = zok && (op > 1e-5f);

        const float* it = intr + ((size_t)b * kV + v) * 4;
        float fx = it[0], fy = it[1], cx = it[2], cy = it[3];
        float u = camx * fx / camz + cx;
        float vv = camy * fy / camz + cy;
        float sg = fminf(fmaxf((fx + fy) * 0.5f * asf / fmaxf(camz, 0.001f), 0.75f), 10.f);

        bool inb = (u >= -3.f) && (u <= (float)kW + 2.f) && (vv >= -3.f) && (vv <= (float)kH + 2.f);
        bool statsValid = valid0 && inb;

        // wave-reduced sigma/cnt stats (1 atomic pair per wave per view)
        float ssum = statsValid ? sg : 0.f;
        int scnt = statsValid ? 1 : 0;
#pragma unroll
        for (int o = 32; o > 0; o >>= 1) {
            ssum += __shfl_down(ssum, o);
            scnt += __shfl_down(scnt, o);
        }
        if (lane == 0 && scnt > 0) {
            atomicAdd(&sigmaSum[inst], ssum);
            atomicAdd(&cnt[inst], scnt);
        }

        int x0 = (int)floorf(u);
        int y0 = (int)floorf(vv);
        bool emit = statsValid && (x0 >= -2) && (x0 <= kW + 1) && (y0 >= -2) && (y0 <= kH + 1);

        // wave-aggregated entry allocation (1 atomic per wave per view)
        unsigned long long m = __ballot(emit);
        int base = 0;
        if (m) {
            int leader = __ffsll((long long)m) - 1;
            if (lane == leader) base = atomicAdd(entCnt, __popcll(m));
            base = __shfl(base, leader);
        }
        if (emit) {
            int e = base + __popcll(m & ((1ULL << lane) - 1ULL));

            float4* p4 = (float4*)(pay + (size_t)e * 12);
            int keybits = (g << 16) | e;
            p4[0] = make_float4(u, vv, 1.f / fmaxf(sg, 0.001f), aSta);
            p4[1] = make_float4(aDyn, aAll, r, gc);
            p4[2] = make_float4(bcl, camz, __int_as_float(keybits), 0.f);

            // overlapping 64x4 tiles of the footprint [x0-2,x0+2]x[y0-2,y0+2]
            int ilo = x0 - 2 < 0 ? 0 : (x0 - 2) / kTX;
            int ihi = min(kTilesX - 1, (x0 + 2) / kTX);
            int jlo = y0 - 2 < 0 ? 0 : (y0 - 2) / kTY;
            int jhi = min(kTilesY - 1, (y0 + 2) / kTY);
            for (int j = jlo; j <= jhi; ++j)
                for (int i = ilo; i <= ihi; ++i) {
                    int bin = inst * kNTiles + j * kTilesX + i;
                    int idx = atomicAdd(&tileCnt[bin], 1);
                    if (idx < kCAP) tileList[(size_t)bin * kCAP + idx] = (unsigned short)e;
                }
        }
    }
}

// tiled rasterizer: gather own bin, rank-sort by (z,g); composite with 16x4 wave
// sub-blocks (__any(keep) skip); LDS re-map; row-major 256B-segment stores.
__global__ __launch_bounds__(256) void k_tile(const int* __restrict__ tileCnt,
                                              const unsigned short* __restrict__ tileList,
                                              const float* __restrict__ pay,
                                              const float* __restrict__ sem,
                                              float* __restrict__ out,
                                              int* __restrict__ tileTouch) {
    __shared__ __align__(16) char smem[SH_SIZE];
    __shared__ int shT[4];
    unsigned long long* shKey = (unsigned long long*)(smem + SH_KEY);
    float4* shA = (float4*)(smem + SH_A);
    float2* shB = (float2*)(smem + SH_B);
    float*  stage = (float*)(smem + SH_STG);   // overlays shKey/shA/shB-head after composite

    int t = threadIdx.x;
    int tile = blockIdx.x;
    int inst = blockIdx.y;
    int bin = inst * kNTiles + tile;
    int N = tileCnt[bin];
    if (N > kCAP) N = kCAP;

    // gather 2 slots per thread (kCAP = 2*256); records in registers until rank known
    unsigned long long kA = ~0ULL, kB = ~0ULL;
    float4 aA, aB; float2 bA, bB;
#define GATHER(i, kq, aq, bq)                                              \
    {   if (i < N) {                                                       \
            int e = tileList[(size_t)bin * kCAP + i];                      \
            const float4* pp = (const float4*)(pay + (size_t)e * 12);      \
            float4 p0 = pp[0], p1 = pp[1], p2 = pp[2];                     \
            kq = packkey(__float_as_int(p2.y), __float_as_int(p2.z));      \
            shKey[i] = kq;                                                 \
            aq = make_float4(p0.x, p0.y, p0.z, packh2(p0.w, p1.x));        \
            bq = make_float2(packh2(p1.y, p1.z), packh2(p1.w, p2.x));      \
        } }
    GATHER(t, kA, aA, bA)
    GATHER(t + 256, kB, aB, bB)
#undef GATHER
    __syncthreads();

    // rank sort (keys unique: low bits hold entry id)
    int rA = 0, rB = 0;
    for (int j = 0; j < N; ++j) {
        unsigned long long kj = shKey[j];
        rA += (kj < kA); rB += (kj < kB);
    }
    __syncthreads();
    if (t < N)       { shA[rA] = aA; shB[rA] = bA; }
    if (t + 256 < N) { shA[rB] = aB; shB[rB] = bB; }
    if (t < 8) {   // zero padding slots for the prefetch pipeline (no-op records)
        shA[N + t] = make_float4(0.f, 0.f, 0.f, 0.f);
        shB[N + t] = make_float2(0.f, 0.f);
    }
    __syncthreads();

    // composite: wave w owns 16x4 sub-block; lane -> (x = w*16 + (lane&15), y = lane>>4)
    int tx = (tile % kTilesX) * kTX;
    int ty = (tile / kTilesX) * kTY;
    int wv = t >> 6, lane = t & 63;
    int clx = wv * 16 + (lane & 15);     // local x in tile
    int cly = lane >> 4;                 // local y in tile
    float fpx = (float)(tx + clx), fpy = (float)(ty + cly);

    float ad0 = 0.f, ad1 = 0.f, ad2 = 0.f;
    float sr0 = 0.f, sg0 = 0.f, sb0 = 0.f;
    float sr1 = 0.f, sg1 = 0.f, sb1 = 0.f;
    float sr2 = 0.f, sg2 = 0.f, sb2 = 0.f;

    float4 Ac = shA[0]; float2 Bc = shB[0];
    for (int k = 0; k < N; ++k) {
        float4 An = shA[k + 1]; float2 Bn = shB[k + 1];   // unconditional prefetch (pad-safe)
        float dxc = fpx - floorf(Ac.x);
        float dyc = fpy - floorf(Ac.y);
        bool keep = (dxc >= -2.f) && (dxc <= 2.f) && (dyc >= -2.f) && (dyc <= 2.f);
        if (__any(keep)) {                                // skipped iters are exact no-ops
            float du = (Ac.x - fpx) * Ac.z;
            float dv = (Ac.y - fpy) * Ac.z;
            float lb = __expf(-0.5f * (du * du + dv * dv));
            lb = keep ? lb : 0.f;
            float2 sd = unpackh2(Ac.w);   // aSta, aDyn
            float2 ar = unpackh2(Bc.x);   // aAll, r
            float2 gb = unpackh2(Bc.y);   // g, b
            // ad* stays in [0, 0.999] by induction -> clip01(1-ad*) == 1-ad* (exact)
            float la, Tt, ct;
            la = fminf(lb * sd.x, 0.999f);
            Tt = 1.f - ad0; ct = la * Tt;
            ad0 = fminf(ad0 + ct, 0.999f);
            sr0 += ar.y * ct; sg0 += gb.x * ct; sb0 += gb.y * ct;
            la = fminf(lb * sd.y, 0.999f);
            Tt = 1.f - ad1; ct = la * Tt;
            ad1 = fminf(ad1 + ct, 0.999f);
            sr1 += ar.y * ct; sg1 += gb.x * ct; sb1 += gb.y * ct;
            la = fminf(lb * ar.x, 0.999f);
            Tt = 1.f - ad2; ct = la * Tt;
            ad2 = fminf(ad2 + ct, 0.999f);
            sr2 += ar.y * ct; sg2 += gb.x * ct; sb2 += gb.y * ct;
        }
        Ac = An; Bc = Bn;
    }

    // touch: per-wave ballot (bijective pixel mapping -> grouping irrelevant)
    unsigned long long tm = __ballot(ad2 > 1e-6f);
    if ((t & 63) == 0) shT[t >> 6] = __popcll(tm);

    // stage 12 outputs in LDS (overlays sort buffers; stride 68 avoids bank conflicts)
    __syncthreads();   // all composite reads of shA/shB done
    int ci = cly * 68 + clx;
    stage[0 * kStgP + ci] = clip01(sr0);
    stage[1 * kStgP + ci] = clip01(sg0);
    stage[2 * kStgP + ci] = clip01(sb0);
    stage[3 * kStgP + ci] = clip01(sr1);
    stage[4 * kStgP + ci] = clip01(sg1);
    stage[5 * kStgP + ci] = clip01(sb1);
    stage[6 * kStgP + ci] = clip01(sr2);
    stage[7 * kStgP + ci] = clip01(sg2);
    stage[8 * kStgP + ci] = clip01(sb2);
    stage[9 * kStgP + ci] = ad0;
    stage[10 * kStgP + ci] = ad1;
    stage[11 * kStgP + ci] = ad2;
    __syncthreads();

    if (t == 0) tileTouch[bin] = shT[0] + shT[1] + shT[2] + shT[3];

    // store: row-major mapping (wave = one 64px row -> 256B segments, r9-proven)
    int si = (t >> 6) * 68 + (t & 63);
    size_t o = (size_t)(ty + (t >> 6)) * kW + tx + (t & 63);
    size_t ib3 = (size_t)inst * 3;
    out[O_RGB_STA + (ib3 + 0) * kHW + o] = stage[0 * kStgP + si];
    out[O_RGB_STA + (ib3 + 1) * kHW + o] = stage[1 * kStgP + si];
    out[O_RGB_STA + (ib3 + 2) * kHW + o] = stage[2 * kStgP + si];
    out[O_RGB_DYN + (ib3 + 0) * kHW + o] = stage[3 * kStgP + si];
    out[O_RGB_DYN + (ib3 + 1) * kHW + o] = stage[4 * kStgP + si];
    out[O_RGB_DYN + (ib3 + 2) * kHW + o] = stage[5 * kStgP + si];
    out[O_RGB_ALL + (ib3 + 0) * kHW + o] = stage[6 * kStgP + si];
    out[O_RGB_ALL + (ib3 + 1) * kHW + o] = stage[7 * kStgP + si];
    out[O_RGB_ALL + (ib3 + 2) * kHW + o] = stage[8 * kStgP + si];
    out[O_A_STA + (size_t)inst * kHW + o] = stage[9 * kStgP + si];
    out[O_A_DYN + (size_t)inst * kHW + o] = stage[10 * kStgP + si];
    out[O_A_ALL + (size_t)inst * kHW + o] = stage[11 * kStgP + si];
    out[O_SEM + (size_t)inst * kHW + o] = sem[(size_t)inst * kHW + o];   // folded passthrough
}

// 384-thread finalize: wave w reduces instance w's touch counts; LDS combine
__global__ __launch_bounds__(384) void k_fin(const float* __restrict__ sigmaSum,
                                             const int* __restrict__ cnt,
                                             const int* __restrict__ tileTouch,
                                             float* __restrict__ out) {
    __shared__ float shSm[kNI], shTr[kNI];
    int w = threadIdx.x >> 6;      // instance 0..5
    int lane = threadIdx.x & 63;
    int s = 0;
    for (int i = lane; i < kNTiles; i += 64) s += tileTouch[w * kNTiles + i];
#pragma unroll
    for (int o = 32; o > 0; o >>= 1) s += __shfl_down(s, o);
    if (lane == 0) {
        shSm[w] = sigmaSum[w] / fmaxf((float)cnt[w], 1.f);
        shTr[w] = (float)s / (float)kHW;
    }
    __syncthreads();
    if (threadIdx.x == 0) {
        float sm = 0.f, tr = 0.f;
        for (int i = 0; i < kNI; ++i) { sm += shSm[i]; tr += shTr[i]; }
        out[O_SM] = sm / (float)kNI;
        out[O_TR] = tr / (float)kNI;
    }
}

// ---------------- launch ----------------
extern "C" void kernel_launch(void* const* d_in, const int* in_sizes, int n_in,
                              void* d_out, int out_size, void* d_ws, size_t ws_size,
                              hipStream_t stream) {
    const float* centers = (const float*)d_in[0];
    const float* scal    = (const float*)d_in[1];
    const float* feat    = (const float*)d_in[2];
    const float* opac    = (const float*)d_in[3];
    const float* bgp     = (const float*)d_in[4];
    const float* sem     = (const float*)d_in[5];
    const float* intr    = (const float*)d_in[6];
    const float* c2w     = (const float*)d_in[7];
    const float* fpose   = (const float*)d_in[8];
    float* out = (float*)d_out;
    char* ws = (char*)d_ws;

    float* w2c      = (float*)(ws + WS_W2C);
    int*   entCnt   = (int*)(ws + WS_CNTR);
    float* sigmaSum = (float*)(ws + WS_CNTR + 16);
    int*   cnt      = (int*)(ws + WS_CNTR + 48);
    int*   tileCnt  = (int*)(ws + WS_TCNT);
    int*   tileTouch= (int*)(ws + WS_TTOUCH);
    unsigned short* tileList = (unsigned short*)(ws + WS_TLIST);
    float* pay      = (float*)(ws + WS_PAY);

    k_zero<<<(kZeroInts + 255) / 256, 256, 0, stream>>>((int*)(ws + WS_CNTR), c2w, w2c);

    dim3 gpre(kNG / 256, kNBT);
    k_pre<<<gpre, 256, 0, stream>>>(centers, scal, feat, opac, bgp, intr, fpose, w2c,
                                    entCnt, sigmaSum, cnt, tileCnt, tileList, pay);

    dim3 gtile(kNTiles, kNI);
    k_tile<<<gtile, 256, 0, stream>>>(tileCnt, tileList, pay, sem, out, tileTouch);

    k_fin<<<1, 384, 0, stream>>>(sigmaSum, cnt, tileTouch, out);
}